// Round 4
// baseline (311.204 us; speedup 1.0000x reference)
//
#include <hip/hip_runtime.h>
#include <math.h>

// EntNet forward on MI355X.
// Sizes: VOC=32000, MEM=128, NSLOTS=20, NSENT=128, MAXLEN=32, QLEN=16, ANSLEN=8, B=64
//
// R18b: R18 (gate on the MFMA pipe) failed from a WORKSPACE ALIASING bug:
// sTb is 1,048,576 bf16 = 524,288 floats, but WsT was placed at ws+262144,
// overlapping sTb's upper half (t>=64) -> prep corrupted the gate s-plane.
// Fix: WsT = ws + 524288. Kernels byte-identical to R18.
//
// R18 design: g[b] = sigmoid(diag(X.S_t^T)*inv + SK) — the diagonal of a
// 32x32 MFMA tile whose A-fragments (state X) are already loaded for the
// main matmul. Waves 0/1 run a second 8-MFMA chain against bf16 s_t
// fragments; static diag select; sigmoid; write g_l. Deletes the entire
// VALU gate phase (~100 VALU ops/thread/step on all 8 waves).

typedef __attribute__((ext_vector_type(8)))  short bf16x8;
typedef __attribute__((ext_vector_type(16))) float f32x16;

__device__ __forceinline__ unsigned short f2bh(float x) {   // f32 -> bf16 RNE
    unsigned int u = __float_as_uint(x);
    u += 0x7FFFu + ((u >> 16) & 1u);
    return (unsigned short)(u >> 16);
}

// butterfly add with quad-local DPP (xor1: quad_perm[1,0,3,2]=0xB1,
// xor2: quad_perm[2,3,0,1]=0x4E) — ~4cy vs ~35cy ds_swizzle.
__device__ __forceinline__ float dpp_xor1_add(float x) {
    int y = __builtin_amdgcn_update_dpp(0, __float_as_int(x), 0xB1, 0xF, 0xF, true);
    return x + __int_as_float(y);
}
__device__ __forceinline__ float dpp_xor2_add(float x) {
    int y = __builtin_amdgcn_update_dpp(0, __float_as_int(x), 0x4E, 0xF, 0xF, true);
    return x + __int_as_float(y);
}

// LDS-only workgroup barrier: waits own DS ops, does NOT drain vmcnt, so
// prefetched global loads (private register results) stay in flight.
#define LDS_BARRIER() do {                                   \
    asm volatile("s_waitcnt lgkmcnt(0)" ::: "memory");       \
    __builtin_amdgcn_s_barrier();                            \
    asm volatile("" ::: "memory");                           \
} while (0)

// ---------------------------------------------------------------- prep
__global__ __launch_bounds__(128) void prep_kernel(
    const int* __restrict__ ids, const int* __restrict__ ques, const int* __restrict__ ans,
    const float* __restrict__ E, const float* __restrict__ Ww, const float* __restrict__ Wb,
    const float* __restrict__ Vw, const float* __restrict__ Vb, const float* __restrict__ skeys,
    unsigned short* __restrict__ sTb, float* __restrict__ WsT, float* __restrict__ vkey,
    float* __restrict__ qv, float* __restrict__ a1v, float* __restrict__ a2v,
    float* __restrict__ SK)
{
    const int bi  = blockIdx.x;
    const int tid = threadIdx.x;   // 128
    __shared__ float s_l[8][132];
    __shared__ float sk_l[20 * 132];
    __shared__ float k_l[128];
    if (bi < 1024) {
        const int b = bi >> 4;
        const int g = bi & 15;
        for (int r = tid; r < 2560; r += 128) sk_l[(r >> 7) * 132 + (r & 127)] = skeys[r];
        for (int tt = 0; tt < 8; ++tt) {
            const int t     = g * 8 + tt;
            const int token = ids[b * 4096 + t];
            const float v   = E[token * 128 + tid];
            s_l[tt][tid] = v;
            sTb[(t * 64 + b) * 128 + tid] = f2bh(v);   // bf16 plane (t, b, m)
        }
        __syncthreads();
        // Ws rows
        float acc[8];
        const float wbn = Wb[tid];
        #pragma unroll
        for (int i = 0; i < 8; ++i) acc[i] = wbn;
        const float4* wrow = (const float4*)(Ww + tid * 128);
        for (int m4 = 0; m4 < 32; ++m4) {
            const float4 w = wrow[m4];
            #pragma unroll
            for (int tt = 0; tt < 8; ++tt) {
                acc[tt] += s_l[tt][m4*4+0]*w.x + s_l[tt][m4*4+1]*w.y
                         + s_l[tt][m4*4+2]*w.z + s_l[tt][m4*4+3]*w.w;
            }
        }
        for (int tt = 0; tt < 8; ++tt)
            WsT[((g*8+tt) * 64 + b) * 128 + tid] = acc[tt];     // layout (t, b, n)
        // SK[j][t][b] = dot(s_t[b], skeys[j])  (gate key-dot, hoisted from scan)
        for (int idx = tid; idx < 160; idx += 128) {
            const int tt = idx / 20;
            const int jj = idx - tt * 20;
            float d = 0.f;
            for (int m = 0; m < 128; ++m) d += s_l[tt][m] * sk_l[jj * 132 + m];
            SK[(jj * 128 + (g*8 + tt)) * 64 + b] = d;
        }
    } else if (bi < 1044) {
        const int j = bi - 1024;
        k_l[tid] = skeys[j * 128 + tid];
        __syncthreads();
        float acc = Vb[tid];
        const float4* vrow = (const float4*)(Vw + tid * 128);
        for (int m4 = 0; m4 < 32; ++m4) {
            const float4 w = vrow[m4];
            acc += k_l[m4*4]*w.x + k_l[m4*4+1]*w.y + k_l[m4*4+2]*w.z + k_l[m4*4+3]*w.w;
        }
        vkey[j * 128 + tid] = acc;
    } else {
        const int b = bi - 1044;
        float sq = 0.f, s1 = 0.f, s2 = 0.f;
        for (int i = 0; i < 16; ++i) sq += E[ques[b*16+i] * 128 + tid];
        for (int i = 0; i < 8;  ++i) s1 += E[ans[(b*8+i)*2+0] * 128 + tid];
        for (int i = 0; i < 8;  ++i) s2 += E[ans[(b*8+i)*2+1] * 128 + tid];
        qv [b*128+tid] = sq * (1.f/16.f);
        a1v[b*128+tid] = s1 * 0.125f;
        a2v[b*128+tid] = s2 * 0.125f;
    }
}

// ---------------------------------------------------------------- scan (MFMA 32x32, bf16 state)
// One block per slot j. 512 threads = 8 waves, 2 waves/SIMD.
// Each wave owns ONE 32x32 C tile (bt2 = wave&1, nt2 = wave>>1).
// C/D layout [m74/m101]: col = lane&31, row = (reg&3)+8*(reg>>2)+4*(lane>>5).
// Gate = diag of X.S_t^T via a second MFMA chain on waves 0/1 only.
// 2 lgkm-only barriers/step; sf/skg/wsv prefetched in update phase
// (cover ~1 step; lgkm-only barriers keep loads in flight).
__global__ __launch_bounds__(512, 1) void scan_kernel(
    const unsigned short* __restrict__ sTb, const float* __restrict__ WsT,
    const float* __restrict__ vkey, const float* __restrict__ Uw,
    const float* __restrict__ Ub, const float* __restrict__ SK,
    float* __restrict__ h_out)
{
    __shared__ unsigned short AB[64 * 136];   // bf16 state, stride 136 (272B rows)
    __shared__ float g_l[64];
    __shared__ float wred[8];

    const int j    = blockIdx.x;
    const int tid  = threadIdx.x;        // 512
    const int wave = tid >> 6;           // 0..7
    const int lane = tid & 63;
    const int l32  = lane & 31;
    const int q    = lane >> 5;          // 0..1
    const int bt2  = wave & 1;           // b half
    const int nt2  = wave >> 1;          // n quarter
    const int n    = nt2 * 32 + l32;     // owned output column

    // gate lane mapping (waves 0,1): lane covers diag row grow of its tile
    const int  grow  = bt2 * 32 + l32;
    const int  rstar = ((l32 >> 3) << 2) | (l32 & 3);   // reg idx with row==col
    const bool act   = (((l32 >> 2) & 1) == q);         // which q-half holds it

    // ---- one-time: weight fragments -> 32 VGPRs (single bf16 plane, RNE) ----
    bf16x8 b_h[8];
    {
        const int k0 = q * 8;
        #pragma unroll
        for (int kc = 0; kc < 8; ++kc) {
            const float4* src = (const float4*)(Uw + n * 128 + kc * 16 + k0);
            const float4 v0 = src[0], v1 = src[1];
            const float xs[8] = {v0.x,v0.y,v0.z,v0.w, v1.x,v1.y,v1.z,v1.w};
            #pragma unroll
            for (int e = 0; e < 8; ++e) b_h[kc][e] = (short)f2bh(xs[e]);
        }
    }
    for (int i = tid; i < 64 * 136 / 2; i += 512) ((unsigned int*)AB)[i] = 0u;
    const float ubv = Ub[n] + vkey[j * 128 + n];

    // ---- per-thread invariant load offsets (bytes), computed once ----
    unsigned woffB[16];
    #pragma unroll
    for (int r = 0; r < 16; ++r) {
        const int brow = bt2*32 + 4*q + (r & 3) + 8*(r >> 2);
        woffB[r] = (unsigned)((brow * 128 + n) * 4);
    }
    const char* SKj  = (const char*)SK + (size_t)j * 32768;
    const char* sfb  = (const char*)sTb + (size_t)grow * 256;   // + t*16384 + kc*32 + q*16

    // fp32 recurrence state (C layout), registers across steps
    float xprev[16];
    #pragma unroll
    for (int r = 0; r < 16; ++r) xprev[r] = 0.f;

    // ---- prefetched globals for current step ----
    float  wsv[16];
    bf16x8 sf[8];
    float  skg = 0.f;
    {
        const char* pW = (const char*)WsT;
        #pragma unroll
        for (int r = 0; r < 16; ++r) wsv[r] = *(const float*)(pW + woffB[r]);
        if (wave < 2) {
            #pragma unroll
            for (int kc = 0; kc < 8; ++kc)
                sf[kc] = *(const bf16x8*)(sfb + kc * 32 + q * 16);
            skg = *(const float*)(SKj + grow * 4);
        }
    }
    __syncthreads();

    float inv_s = 1.f;                   // true mem = inv_s * bf16(state)

    for (int t = 0; t < 128; ++t) {
        const int tn = (t < 127) ? t + 1 : 127;

        // ---- bias fold (off critical path; wsv vmcnt satisfied long ago) ----
        float wsvu[16];
        #pragma unroll
        for (int r = 0; r < 16; ++r) wsvu[r] = wsv[r] + ubv;

        // ---- main MFMA: acc = X(32b x 128m) . Uw(32n x 128m)^T ----
        f32x16 acc0 = {0.f,0.f,0.f,0.f,0.f,0.f,0.f,0.f,
                       0.f,0.f,0.f,0.f,0.f,0.f,0.f,0.f};
        f32x16 acc1 = acc0;
        const unsigned short* arow = AB + (bt2*32 + l32) * 136 + q * 8;
        #pragma unroll
        for (int kc = 0; kc < 8; ++kc) {
            const bf16x8 a = *(const bf16x8*)(arow + kc * 16);
            if (kc & 1) acc1 = __builtin_amdgcn_mfma_f32_32x32x16_bf16(a, b_h[kc], acc1, 0, 0, 0);
            else        acc0 = __builtin_amdgcn_mfma_f32_32x32x16_bf16(a, b_h[kc], acc0, 0, 0, 0);
        }
        acc0 += acc1;

        // ---- gate via MFMA diagonal (waves 0,1 only) ----
        if (wave < 2) {
            f32x16 gc0 = {0.f,0.f,0.f,0.f,0.f,0.f,0.f,0.f,
                          0.f,0.f,0.f,0.f,0.f,0.f,0.f,0.f};
            f32x16 gc1 = gc0;
            #pragma unroll
            for (int kc = 0; kc < 8; ++kc) {
                const bf16x8 a = *(const bf16x8*)(arow + kc * 16);
                if (kc & 1) gc1 = __builtin_amdgcn_mfma_f32_32x32x16_bf16(a, sf[kc], gc1, 0, 0, 0);
                else        gc0 = __builtin_amdgcn_mfma_f32_32x32x16_bf16(a, sf[kc], gc0, 0, 0, 0);
            }
            gc0 += gc1;
            float dsum = 0.f;
            #pragma unroll
            for (int r = 0; r < 16; ++r) dsum = (r == rstar) ? gc0[r] : dsum;
            if (act) {
                const float e = __expf(-(inv_s * dsum + skg));
                g_l[grow] = __builtin_amdgcn_rcpf(1.f + e);   // fast sigmoid
            }
        }
        LDS_BARRIER();   // B1: AB reads complete; g_l visible (no vmcnt drain)

        // ---- update owned (b, n) cells in C layout ----
        const float4 gA = *(const float4*)(g_l + bt2*32 + 4*q + 0);
        const float4 gB = *(const float4*)(g_l + bt2*32 + 4*q + 8);
        const float4 gC = *(const float4*)(g_l + bt2*32 + 4*q + 16);
        const float4 gD = *(const float4*)(g_l + bt2*32 + 4*q + 24);
        const float gr[16] = {gA.x,gA.y,gA.z,gA.w, gB.x,gB.y,gB.z,gB.w,
                              gC.x,gC.y,gC.z,gC.w, gD.x,gD.y,gD.z,gD.w};
        float sq0 = 0.f, sq1 = 0.f;
        #pragma unroll
        for (int r = 0; r < 16; ++r) {
            const int brow = bt2*32 + 4*q + (r & 3) + 8*(r >> 2);
            float hr = fmaf(inv_s, acc0[r], wsvu[r]);
            hr = fmaxf(hr, 0.f);                          // h_cand
            const float x = fmaf(inv_s, xprev[r], gr[r] * hr);
            xprev[r] = x;                                 // fp32 recurrence
            AB[brow*136 + n] = (unsigned short)(__float_as_uint(x) >> 16);  // trunc pack
            if (r & 1) sq1 = fmaf(x, x, sq1); else sq0 = fmaf(x, x, sq0);
        }

        // ---- prefetch t+1 globals (use next step; lgkm barriers keep in flight) ----
        {
            const char* pW = (const char*)WsT + (size_t)tn * 32768;
            #pragma unroll
            for (int r = 0; r < 16; ++r)
                wsv[r] = *(const float*)(pW + woffB[r]);
            if (wave < 2) {
                const char* pS = sfb + (size_t)tn * 16384;
                #pragma unroll
                for (int kc = 0; kc < 8; ++kc)
                    sf[kc] = *(const bf16x8*)(pS + kc * 32 + q * 16);
                skg = *(const float*)(SKj + (size_t)tn * 256 + grow * 4);
            }
        }

        float ssq = sq0 + sq1;
        ssq = dpp_xor1_add(ssq);
        ssq = dpp_xor2_add(ssq);
        ssq += __shfl_xor(ssq, 4, 64);
        ssq += __shfl_xor(ssq, 8, 64);
        ssq += __shfl_xor(ssq, 16, 64);
        ssq += __shfl_xor(ssq, 32, 64);
        if (lane == 0) wred[wave] = ssq;
        LDS_BARRIER();   // B2: AB writes + wred visible (loads stay in flight)
        const float4 w0 = *(const float4*)(wred);
        const float4 w1 = *(const float4*)(wred + 4);
        inv_s = __builtin_amdgcn_rsqf(w0.x+w0.y+w0.z+w0.w + w1.x+w1.y+w1.z+w1.w);
    }

    // ---- h = inv * state (fp32 path), layout (b, j, m) ----
    #pragma unroll
    for (int r = 0; r < 16; ++r) {
        const int brow = bt2*32 + 4*q + (r & 3) + 8*(r >> 2);
        h_out[(brow*20 + j)*128 + n] = inv_s * xprev[r];
    }
}

// ---------------------------------------------------------------- final
__global__ __launch_bounds__(128) void final_kernel(
    const float* __restrict__ h, const float* __restrict__ qv,
    const float* __restrict__ a1v, const float* __restrict__ a2v,
    const float* __restrict__ Hw, const float* __restrict__ Hb,
    float* __restrict__ out)
{
    const int b   = blockIdx.x;
    const int tid = threadIdx.x;    // 128
    __shared__ float hb[20][128];
    __shared__ float ql[128];
    __shared__ float ul[128];
    __shared__ float pl[20];
    __shared__ float lgt[20];
    __shared__ float red1[2], red2[2];

    for (int jj = 0; jj < 20; ++jj) hb[jj][tid] = h[(b*20+jj)*128 + tid];
    ql[tid] = qv[b*128 + tid];
    __syncthreads();
    if (tid < 20) {
        float d = 0.f;
        for (int m = 0; m < 128; ++m) d += hb[tid][m] * ql[m];
        lgt[tid] = d;
    }
    __syncthreads();
    if (tid == 0) {
        float mx = lgt[0];
        for (int jj = 1; jj < 20; ++jj) mx = fmaxf(mx, lgt[jj]);
        float s = 0.f;
        for (int jj = 0; jj < 20; ++jj) { const float e = expf(lgt[jj]-mx); pl[jj] = e; s += e; }
        const float is = 1.f / s;
        for (int jj = 0; jj < 20; ++jj) pl[jj] *= is;
    }
    __syncthreads();
    float u = 0.f;
    for (int jj = 0; jj < 20; ++jj) u += pl[jj] * hb[jj][tid];
    ul[tid] = u;
    __syncthreads();
    float acc = ql[tid] + Hb[tid];
    const float4* hwr = (const float4*)(Hw + tid*128);
    for (int m4 = 0; m4 < 32; ++m4) {
        const float4 w = hwr[m4];
        acc += ul[m4*4]*w.x + ul[m4*4+1]*w.y + ul[m4*4+2]*w.z + ul[m4*4+3]*w.w;
    }
    const float r  = fmaxf(acc, 0.f);
    float y1 = r * a1v[b*128+tid];
    float y2 = r * a2v[b*128+tid];
    #pragma unroll
    for (int mask = 1; mask < 64; mask <<= 1) {
        y1 += __shfl_xor(y1, mask, 64);
        y2 += __shfl_xor(y2, mask, 64);
    }
    if ((tid & 63) == 0) { red1[tid>>6] = y1; red2[tid>>6] = y2; }
    __syncthreads();
    if (tid == 0) {
        const float z1 = red1[0] + red1[1];
        const float z2 = red2[0] + red2[1];
        const float mx = fmaxf(z1, z2);
        const float e1 = expf(z1-mx), e2 = expf(z2-mx);
        const float s  = e1 + e2;
        out[b*2+0] = e1 / s;
        out[b*2+1] = e2 / s;
    }
}

// ---------------------------------------------------------------- launch
extern "C" void kernel_launch(void* const* d_in, const int* in_sizes, int n_in,
                              void* d_out, int out_size, void* d_ws, size_t ws_size,
                              hipStream_t stream)
{
    const int*   ids  = (const int*)  d_in[0];
    const int*   ques = (const int*)  d_in[1];
    const int*   ans  = (const int*)  d_in[2];
    const float* E    = (const float*)d_in[3];
    const float* Uw   = (const float*)d_in[4];
    const float* Ubv  = (const float*)d_in[5];
    const float* Vw   = (const float*)d_in[6];
    const float* Vb   = (const float*)d_in[7];
    const float* Ww   = (const float*)d_in[8];
    const float* Wb   = (const float*)d_in[9];
    const float* sk   = (const float*)d_in[10];
    const float* Hw   = (const float*)d_in[11];
    const float* Hb   = (const float*)d_in[12];

    // workspace (floats): sTb bf16[1048576] = 524288 floats | WsT 1048576 |
    //   vkey 2560 | qv/a1v/a2v 3*8192 | h 163840 | SK 163840   (~7.7 MB)
    float* ws   = (float*)d_ws;
    unsigned short* sTb = (unsigned short*)ws;        // 1048576 ushort = 524288 floats
    float* WsT  = ws    + 524288;                     // FIX: was +262144 (aliased sTb!)
    float* vkey = WsT   + 1048576;
    float* qv   = vkey  + 2560;
    float* a1v  = qv    + 8192;
    float* a2v  = a1v   + 8192;
    float* h    = a2v   + 8192;
    float* SK   = h     + 163840;

    prep_kernel<<<1108, 128, 0, stream>>>(ids, ques, ans, E, Ww, Wb, Vw, Vb, sk,
                                          sTb, WsT, vkey, qv, a1v, a2v, SK);
    scan_kernel<<<20, 512, 0, stream>>>(sTb, WsT, vkey, Uw, Ubv, SK, h);
    final_kernel<<<64, 128, 0, stream>>>(h, qv, a1v, a2v, Hw, Hb, (float*)d_out);
}

// Round 5
// 302.984 us; speedup vs baseline: 1.0271x; 1.0271x over previous
//
#include <hip/hip_runtime.h>
#include <math.h>

// EntNet forward on MI355X.
// Sizes: VOC=32000, MEM=128, NSLOTS=20, NSENT=128, MAXLEN=32, QLEN=16, ANSLEN=8, B=64
//
// R19: R18b put the gate on the MFMA pipe but regressed (188->210us):
// 8 extra 32x32 MFMAs in a 4-deep chain on waves 0/1 only, issued AFTER
// the main block behind a branch -> ~400cy serial tail on SIMD0/1 while
// waves 2-7 idle at B1. Fix:
//  - gate = four 16x16 diag blocks; wave w (0..3) computes block w with
//    4x mfma_f32_16x16x32_bf16 (2 chains of 2) -> balanced across SIMDs;
//  - gate issued BEFORE the main 8-MFMA block so its chain latency hides
//    under main issue; only select+sigmoid tail (~40cy) exposed;
//  - diag select is 3 cndmask (reg = c&3); sf shrinks to 4 frags.
// C/D 16x16 layout [m89]: col=lane&15, row=(lane>>4)*4+reg.
// A/B 16x16x32: row/col=lane&15, k=(lane>>4)*8+e + kc*32.

typedef __attribute__((ext_vector_type(8)))  short bf16x8;
typedef __attribute__((ext_vector_type(16))) float f32x16;
typedef __attribute__((ext_vector_type(4)))  float f32x4;

__device__ __forceinline__ unsigned short f2bh(float x) {   // f32 -> bf16 RNE
    unsigned int u = __float_as_uint(x);
    u += 0x7FFFu + ((u >> 16) & 1u);
    return (unsigned short)(u >> 16);
}

// butterfly add with quad-local DPP (xor1: quad_perm[1,0,3,2]=0xB1,
// xor2: quad_perm[2,3,0,1]=0x4E) — ~4cy vs ~35cy ds_swizzle.
__device__ __forceinline__ float dpp_xor1_add(float x) {
    int y = __builtin_amdgcn_update_dpp(0, __float_as_int(x), 0xB1, 0xF, 0xF, true);
    return x + __int_as_float(y);
}
__device__ __forceinline__ float dpp_xor2_add(float x) {
    int y = __builtin_amdgcn_update_dpp(0, __float_as_int(x), 0x4E, 0xF, 0xF, true);
    return x + __int_as_float(y);
}

// LDS-only workgroup barrier: waits own DS ops, does NOT drain vmcnt, so
// prefetched global loads (private register results) stay in flight.
#define LDS_BARRIER() do {                                   \
    asm volatile("s_waitcnt lgkmcnt(0)" ::: "memory");       \
    __builtin_amdgcn_s_barrier();                            \
    asm volatile("" ::: "memory");                           \
} while (0)

// ---------------------------------------------------------------- prep
__global__ __launch_bounds__(128) void prep_kernel(
    const int* __restrict__ ids, const int* __restrict__ ques, const int* __restrict__ ans,
    const float* __restrict__ E, const float* __restrict__ Ww, const float* __restrict__ Wb,
    const float* __restrict__ Vw, const float* __restrict__ Vb, const float* __restrict__ skeys,
    unsigned short* __restrict__ sTb, float* __restrict__ WsT, float* __restrict__ vkey,
    float* __restrict__ qv, float* __restrict__ a1v, float* __restrict__ a2v,
    float* __restrict__ SK)
{
    const int bi  = blockIdx.x;
    const int tid = threadIdx.x;   // 128
    __shared__ float s_l[8][132];
    __shared__ float sk_l[20 * 132];
    __shared__ float k_l[128];
    if (bi < 1024) {
        const int b = bi >> 4;
        const int g = bi & 15;
        for (int r = tid; r < 2560; r += 128) sk_l[(r >> 7) * 132 + (r & 127)] = skeys[r];
        for (int tt = 0; tt < 8; ++tt) {
            const int t     = g * 8 + tt;
            const int token = ids[b * 4096 + t];
            const float v   = E[token * 128 + tid];
            s_l[tt][tid] = v;
            sTb[(t * 64 + b) * 128 + tid] = f2bh(v);   // bf16 plane (t, b, m)
        }
        __syncthreads();
        // Ws rows
        float acc[8];
        const float wbn = Wb[tid];
        #pragma unroll
        for (int i = 0; i < 8; ++i) acc[i] = wbn;
        const float4* wrow = (const float4*)(Ww + tid * 128);
        for (int m4 = 0; m4 < 32; ++m4) {
            const float4 w = wrow[m4];
            #pragma unroll
            for (int tt = 0; tt < 8; ++tt) {
                acc[tt] += s_l[tt][m4*4+0]*w.x + s_l[tt][m4*4+1]*w.y
                         + s_l[tt][m4*4+2]*w.z + s_l[tt][m4*4+3]*w.w;
            }
        }
        for (int tt = 0; tt < 8; ++tt)
            WsT[((g*8+tt) * 64 + b) * 128 + tid] = acc[tt];     // layout (t, b, n)
        // SK[j][t][b] = dot(s_t[b], skeys[j])  (gate key-dot, hoisted from scan)
        for (int idx = tid; idx < 160; idx += 128) {
            const int tt = idx / 20;
            const int jj = idx - tt * 20;
            float d = 0.f;
            for (int m = 0; m < 128; ++m) d += s_l[tt][m] * sk_l[jj * 132 + m];
            SK[(jj * 128 + (g*8 + tt)) * 64 + b] = d;
        }
    } else if (bi < 1044) {
        const int j = bi - 1024;
        k_l[tid] = skeys[j * 128 + tid];
        __syncthreads();
        float acc = Vb[tid];
        const float4* vrow = (const float4*)(Vw + tid * 128);
        for (int m4 = 0; m4 < 32; ++m4) {
            const float4 w = vrow[m4];
            acc += k_l[m4*4]*w.x + k_l[m4*4+1]*w.y + k_l[m4*4+2]*w.z + k_l[m4*4+3]*w.w;
        }
        vkey[j * 128 + tid] = acc;
    } else {
        const int b = bi - 1044;
        float sq = 0.f, s1 = 0.f, s2 = 0.f;
        for (int i = 0; i < 16; ++i) sq += E[ques[b*16+i] * 128 + tid];
        for (int i = 0; i < 8;  ++i) s1 += E[ans[(b*8+i)*2+0] * 128 + tid];
        for (int i = 0; i < 8;  ++i) s2 += E[ans[(b*8+i)*2+1] * 128 + tid];
        qv [b*128+tid] = sq * (1.f/16.f);
        a1v[b*128+tid] = s1 * 0.125f;
        a2v[b*128+tid] = s2 * 0.125f;
    }
}

// ---------------------------------------------------------------- scan (MFMA 32x32, bf16 state)
// One block per slot j. 512 threads = 8 waves, 2 waves/SIMD.
// Each wave owns ONE 32x32 C tile of the main matmul (bt2=wave&1, nt2=wave>>1).
// Main C/D layout [m74/m101]: col=lane&31, row=(reg&3)+8*(reg>>2)+4*(lane>>5).
// Gate: wave w in {0..3} computes diag block w (rows 16w..16w+15) of
// X.S_t^T via 4x mfma 16x16x32, issued BEFORE the main block.
// 2 lgkm-only barriers/step; sf/skg/wsv prefetched in update phase.
__global__ __launch_bounds__(512, 1) void scan_kernel(
    const unsigned short* __restrict__ sTb, const float* __restrict__ WsT,
    const float* __restrict__ vkey, const float* __restrict__ Uw,
    const float* __restrict__ Ub, const float* __restrict__ SK,
    float* __restrict__ h_out)
{
    __shared__ unsigned short AB[64 * 136];   // bf16 state, stride 136 (272B rows)
    __shared__ float g_l[64];
    __shared__ float wred[8];

    const int j    = blockIdx.x;
    const int tid  = threadIdx.x;        // 512
    const int wave = tid >> 6;           // 0..7
    const int lane = tid & 63;
    const int l32  = lane & 31;
    const int q    = lane >> 5;          // 0..1
    const int bt2  = wave & 1;           // b half
    const int nt2  = wave >> 1;          // n quarter
    const int n    = nt2 * 32 + l32;     // owned output column

    // gate lane mapping (waves 0..3): wave w owns diag rows 16w..16w+15
    const int  c16   = lane & 15;                       // col within 16-block
    const int  kg16  = lane >> 4;                       // k-group 0..3
    const int  grow  = wave * 16 + c16;                 // global b (valid wave<4)
    const bool act   = (kg16 == (c16 >> 2));            // lane holding diag elem
    const int  rsel  = lane & 3;                        // reg index of diag elem

    // ---- one-time: weight fragments -> 32 VGPRs (single bf16 plane, RNE) ----
    bf16x8 b_h[8];
    {
        const int k0 = q * 8;
        #pragma unroll
        for (int kc = 0; kc < 8; ++kc) {
            const float4* src = (const float4*)(Uw + n * 128 + kc * 16 + k0);
            const float4 v0 = src[0], v1 = src[1];
            const float xs[8] = {v0.x,v0.y,v0.z,v0.w, v1.x,v1.y,v1.z,v1.w};
            #pragma unroll
            for (int e = 0; e < 8; ++e) b_h[kc][e] = (short)f2bh(xs[e]);
        }
    }
    for (int i = tid; i < 64 * 136 / 2; i += 512) ((unsigned int*)AB)[i] = 0u;
    const float ubv = Ub[n] + vkey[j * 128 + n];

    // ---- per-thread invariant load offsets (bytes), computed once ----
    unsigned woffB[16];
    #pragma unroll
    for (int r = 0; r < 16; ++r) {
        const int brow = bt2*32 + 4*q + (r & 3) + 8*(r >> 2);
        woffB[r] = (unsigned)((brow * 128 + n) * 4);
    }
    const char* SKj = (const char*)SK + (size_t)j * 32768;
    // gate B-frag source: s_t[b=grow][k=kg16*8+e + kc*32] in sTb (t,b,m)
    const char* sfb = (const char*)sTb + (size_t)grow * 256 + (size_t)kg16 * 16;
    // gate A-frag source: AB[grow][kg16*8 + kc*32] (elements)
    const unsigned short* a16 = AB + grow * 136 + kg16 * 8;

    // fp32 recurrence state (C layout), registers across steps
    float xprev[16];
    #pragma unroll
    for (int r = 0; r < 16; ++r) xprev[r] = 0.f;

    // ---- prefetched globals for current step ----
    float  wsv[16];
    bf16x8 sf[4];
    float  skg = 0.f;
    {
        const char* pW = (const char*)WsT;
        #pragma unroll
        for (int r = 0; r < 16; ++r) wsv[r] = *(const float*)(pW + woffB[r]);
        if (wave < 4) {
            #pragma unroll
            for (int kc = 0; kc < 4; ++kc)
                sf[kc] = *(const bf16x8*)(sfb + kc * 64);
            skg = *(const float*)(SKj + grow * 4);
        }
    }
    __syncthreads();

    float inv_s = 1.f;                   // true mem = inv_s * bf16(state)

    for (int t = 0; t < 128; ++t) {
        const int tn = (t < 127) ? t + 1 : 127;

        // ---- bias fold (off critical path; wsv vmcnt satisfied long ago) ----
        float wsvu[16];
        #pragma unroll
        for (int r = 0; r < 16; ++r) wsvu[r] = wsv[r] + ubv;

        // ---- gate first (waves 0..3): 4x 16x16x32 MFMA, chain hides under main ----
        float dsum = 0.f;
        if (wave < 4) {
            f32x4 gc0 = {0.f,0.f,0.f,0.f};
            f32x4 gc1 = gc0;
            #pragma unroll
            for (int kc = 0; kc < 4; ++kc) {
                const bf16x8 a = *(const bf16x8*)(a16 + kc * 32);
                if (kc & 1) gc1 = __builtin_amdgcn_mfma_f32_16x16x32_bf16(a, sf[kc], gc1, 0, 0, 0);
                else        gc0 = __builtin_amdgcn_mfma_f32_16x16x32_bf16(a, sf[kc], gc0, 0, 0, 0);
            }
            const f32x4 gc = gc0 + gc1;
            const float d01 = (rsel & 1) ? gc[1] : gc[0];
            const float d23 = (rsel & 1) ? gc[3] : gc[2];
            dsum = (rsel & 2) ? d23 : d01;
        }

        // ---- main MFMA: acc = X(32b x 128m) . Uw(32n x 128m)^T ----
        f32x16 acc0 = {0.f,0.f,0.f,0.f,0.f,0.f,0.f,0.f,
                       0.f,0.f,0.f,0.f,0.f,0.f,0.f,0.f};
        f32x16 acc1 = acc0;
        const unsigned short* arow = AB + (bt2*32 + l32) * 136 + q * 8;
        #pragma unroll
        for (int kc = 0; kc < 8; ++kc) {
            const bf16x8 a = *(const bf16x8*)(arow + kc * 16);
            if (kc & 1) acc1 = __builtin_amdgcn_mfma_f32_32x32x16_bf16(a, b_h[kc], acc1, 0, 0, 0);
            else        acc0 = __builtin_amdgcn_mfma_f32_32x32x16_bf16(a, b_h[kc], acc0, 0, 0, 0);
        }
        acc0 += acc1;

        // ---- gate tail: sigmoid + g_l write (16 lanes per gate wave) ----
        if (wave < 4 && act) {
            const float e = __expf(-(inv_s * dsum + skg));
            g_l[grow] = __builtin_amdgcn_rcpf(1.f + e);   // fast sigmoid
        }
        LDS_BARRIER();   // B1: AB reads complete; g_l visible (no vmcnt drain)

        // ---- update owned (b, n) cells in C layout ----
        const float4 gA = *(const float4*)(g_l + bt2*32 + 4*q + 0);
        const float4 gB = *(const float4*)(g_l + bt2*32 + 4*q + 8);
        const float4 gC = *(const float4*)(g_l + bt2*32 + 4*q + 16);
        const float4 gD = *(const float4*)(g_l + bt2*32 + 4*q + 24);
        const float gr[16] = {gA.x,gA.y,gA.z,gA.w, gB.x,gB.y,gB.z,gB.w,
                              gC.x,gC.y,gC.z,gC.w, gD.x,gD.y,gD.z,gD.w};
        float sq0 = 0.f, sq1 = 0.f;
        #pragma unroll
        for (int r = 0; r < 16; ++r) {
            const int brow = bt2*32 + 4*q + (r & 3) + 8*(r >> 2);
            float hr = fmaf(inv_s, acc0[r], wsvu[r]);
            hr = fmaxf(hr, 0.f);                          // h_cand
            const float x = fmaf(inv_s, xprev[r], gr[r] * hr);
            xprev[r] = x;                                 // fp32 recurrence
            AB[brow*136 + n] = (unsigned short)(__float_as_uint(x) >> 16);  // trunc pack
            if (r & 1) sq1 = fmaf(x, x, sq1); else sq0 = fmaf(x, x, sq0);
        }

        // ---- prefetch t+1 globals (use next step; lgkm barriers keep in flight) ----
        {
            const char* pW = (const char*)WsT + (size_t)tn * 32768;
            #pragma unroll
            for (int r = 0; r < 16; ++r)
                wsv[r] = *(const float*)(pW + woffB[r]);
            if (wave < 4) {
                const char* pS = sfb + (size_t)tn * 16384;
                #pragma unroll
                for (int kc = 0; kc < 4; ++kc)
                    sf[kc] = *(const bf16x8*)(pS + kc * 64);
                skg = *(const float*)(SKj + (size_t)tn * 256 + grow * 4);
            }
        }

        float ssq = sq0 + sq1;
        ssq = dpp_xor1_add(ssq);
        ssq = dpp_xor2_add(ssq);
        ssq += __shfl_xor(ssq, 4, 64);
        ssq += __shfl_xor(ssq, 8, 64);
        ssq += __shfl_xor(ssq, 16, 64);
        ssq += __shfl_xor(ssq, 32, 64);
        if (lane == 0) wred[wave] = ssq;
        LDS_BARRIER();   // B2: AB writes + wred visible (loads stay in flight)
        const float4 w0 = *(const float4*)(wred);
        const float4 w1 = *(const float4*)(wred + 4);
        inv_s = __builtin_amdgcn_rsqf(w0.x+w0.y+w0.z+w0.w + w1.x+w1.y+w1.z+w1.w);
    }

    // ---- h = inv * state (fp32 path), layout (b, j, m) ----
    #pragma unroll
    for (int r = 0; r < 16; ++r) {
        const int brow = bt2*32 + 4*q + (r & 3) + 8*(r >> 2);
        h_out[(brow*20 + j)*128 + n] = inv_s * xprev[r];
    }
}

// ---------------------------------------------------------------- final
__global__ __launch_bounds__(128) void final_kernel(
    const float* __restrict__ h, const float* __restrict__ qv,
    const float* __restrict__ a1v, const float* __restrict__ a2v,
    const float* __restrict__ Hw, const float* __restrict__ Hb,
    float* __restrict__ out)
{
    const int b   = blockIdx.x;
    const int tid = threadIdx.x;    // 128
    __shared__ float hb[20][128];
    __shared__ float ql[128];
    __shared__ float ul[128];
    __shared__ float pl[20];
    __shared__ float lgt[20];
    __shared__ float red1[2], red2[2];

    for (int jj = 0; jj < 20; ++jj) hb[jj][tid] = h[(b*20+jj)*128 + tid];
    ql[tid] = qv[b*128 + tid];
    __syncthreads();
    if (tid < 20) {
        float d = 0.f;
        for (int m = 0; m < 128; ++m) d += hb[tid][m] * ql[m];
        lgt[tid] = d;
    }
    __syncthreads();
    if (tid == 0) {
        float mx = lgt[0];
        for (int jj = 1; jj < 20; ++jj) mx = fmaxf(mx, lgt[jj]);
        float s = 0.f;
        for (int jj = 0; jj < 20; ++jj) { const float e = expf(lgt[jj]-mx); pl[jj] = e; s += e; }
        const float is = 1.f / s;
        for (int jj = 0; jj < 20; ++jj) pl[jj] *= is;
    }
    __syncthreads();
    float u = 0.f;
    for (int jj = 0; jj < 20; ++jj) u += pl[jj] * hb[jj][tid];
    ul[tid] = u;
    __syncthreads();
    float acc = ql[tid] + Hb[tid];
    const float4* hwr = (const float4*)(Hw + tid*128);
    for (int m4 = 0; m4 < 32; ++m4) {
        const float4 w = hwr[m4];
        acc += ul[m4*4]*w.x + ul[m4*4+1]*w.y + ul[m4*4+2]*w.z + ul[m4*4+3]*w.w;
    }
    const float r  = fmaxf(acc, 0.f);
    float y1 = r * a1v[b*128+tid];
    float y2 = r * a2v[b*128+tid];
    #pragma unroll
    for (int mask = 1; mask < 64; mask <<= 1) {
        y1 += __shfl_xor(y1, mask, 64);
        y2 += __shfl_xor(y2, mask, 64);
    }
    if ((tid & 63) == 0) { red1[tid>>6] = y1; red2[tid>>6] = y2; }
    __syncthreads();
    if (tid == 0) {
        const float z1 = red1[0] + red1[1];
        const float z2 = red2[0] + red2[1];
        const float mx = fmaxf(z1, z2);
        const float e1 = expf(z1-mx), e2 = expf(z2-mx);
        const float s  = e1 + e2;
        out[b*2+0] = e1 / s;
        out[b*2+1] = e2 / s;
    }
}

// ---------------------------------------------------------------- launch
extern "C" void kernel_launch(void* const* d_in, const int* in_sizes, int n_in,
                              void* d_out, int out_size, void* d_ws, size_t ws_size,
                              hipStream_t stream)
{
    const int*   ids  = (const int*)  d_in[0];
    const int*   ques = (const int*)  d_in[1];
    const int*   ans  = (const int*)  d_in[2];
    const float* E    = (const float*)d_in[3];
    const float* Uw   = (const float*)d_in[4];
    const float* Ubv  = (const float*)d_in[5];
    const float* Vw   = (const float*)d_in[6];
    const float* Vb   = (const float*)d_in[7];
    const float* Ww   = (const float*)d_in[8];
    const float* Wb   = (const float*)d_in[9];
    const float* sk   = (const float*)d_in[10];
    const float* Hw   = (const float*)d_in[11];
    const float* Hb   = (const float*)d_in[12];

    // workspace (floats): sTb bf16[1048576] = 524288 floats | WsT 1048576 |
    //   vkey 2560 | qv/a1v/a2v 3*8192 | h 163840 | SK 163840   (~7.7 MB)
    float* ws   = (float*)d_ws;
    unsigned short* sTb = (unsigned short*)ws;        // 1048576 ushort = 524288 floats
    float* WsT  = ws    + 524288;
    float* vkey = WsT   + 1048576;
    float* qv   = vkey  + 2560;
    float* a1v  = qv    + 8192;
    float* a2v  = a1v   + 8192;
    float* h    = a2v   + 8192;
    float* SK   = h     + 163840;

    prep_kernel<<<1108, 128, 0, stream>>>(ids, ques, ans, E, Ww, Wb, Vw, Vb, sk,
                                          sTb, WsT, vkey, qv, a1v, a2v, SK);
    scan_kernel<<<20, 512, 0, stream>>>(sTb, WsT, vkey, Uw, Ubv, SK, h);
    final_kernel<<<64, 128, 0, stream>>>(h, qv, a1v, a2v, Hw, Hb, (float*)d_out);
}